// Round 1
// baseline (4208.236 us; speedup 1.0000x reference)
//
#include <hip/hip_runtime.h>
#include <math.h>

#define BB 8
#define TT 128
#define NN 512
#define HH 4
#define DD 2048      // N*HID
#define EE 16384

// ---------------- CSR build (edges are the same for every timestep) ----------------

__global__ void k_csr_zero(int* __restrict__ counts, int* __restrict__ fill) {
    int i = threadIdx.x;
    counts[i] = 0;
    fill[i] = 0;
}

__global__ void k_csr_count(const int* __restrict__ ei, int* __restrict__ counts) {
    int e = blockIdx.x * blockDim.x + threadIdx.x;
    if (e < EE) atomicAdd(&counts[ei[EE + e]], 1);
}

__global__ void k_csr_scan(const int* __restrict__ counts, int* __restrict__ offs) {
    // single-thread serial scan over 512 nodes — negligible
    int s = 0;
    for (int i = 0; i < NN; ++i) { offs[i] = s; s += counts[i]; }
    offs[NN] = s;
}

__global__ void k_csr_fill(const int* __restrict__ ei, const int* __restrict__ offs,
                           int* __restrict__ fill, int* __restrict__ csr_src) {
    int e = blockIdx.x * blockDim.x + threadIdx.x;
    if (e < EE) {
        int d = ei[EE + e];
        int pos = atomicAdd(&fill[d], 1);
        csr_src[offs[d] + pos] = ei[e];
    }
}

// ---------------- GAT ----------------
// batch 0 (nodes with real in-edges + self loop): softmax attention over CSR list
__global__ void k_gat0(const float* __restrict__ xseq, const float* __restrict__ W,
                       const float* __restrict__ as, const float* __restrict__ ad,
                       const float* __restrict__ bias, const int* __restrict__ offs,
                       const int* __restrict__ csr_src, float* __restrict__ seqout) {
    __shared__ float xr[NN];
    const int t = blockIdx.x;
    const int j = threadIdx.x;
    xr[j] = xseq[t * NN + j];        // x_sequence[0, t, j]
    __syncthreads();

    const float w0 = W[0], w1 = W[1], w2 = W[2], w3 = W[3];
    const float cs = w0 * as[0] + w1 * as[1] + w2 * as[2] + w3 * as[3];
    const float cd = w0 * ad[0] + w1 * ad[1] + w2 * ad[2] + w3 * ad[3];

    const float xj = xr[j];
    const float ed = cd * xj;
    float e0 = (cs + cd) * xj;
    e0 = e0 > 0.f ? e0 : 0.2f * e0;                    // leaky_relu self-loop

    const int s0 = offs[j], s1 = offs[j + 1];
    float m = e0;
    for (int p = s0; p < s1; ++p) {
        float e = cs * xr[csr_src[p]] + ed;
        e = e > 0.f ? e : 0.2f * e;
        m = fmaxf(m, e);
    }
    float den = expf(e0 - m);
    float num = den * xj;
    for (int p = s0; p < s1; ++p) {
        int s = csr_src[p];
        float e = cs * xr[s] + ed;
        e = e > 0.f ? e : 0.2f * e;
        float wgt = expf(e - m);
        den += wgt;
        num += wgt * xr[s];
    }
    const float y = num / den;

    float4 o;
    o.x = fmaxf(w0 * y + bias[0], 0.f);
    o.y = fmaxf(w1 * y + bias[1], 0.f);
    o.z = fmaxf(w2 * y + bias[2], 0.f);
    o.w = fmaxf(w3 * y + bias[3], 0.f);
    *(float4*)(seqout + (size_t)t * BB * DD + (size_t)j * HH) = o;
}

// batches 1..7: self-loop only → out = relu(W[k]*x + bias[k])
__global__ void k_gat_rest(const float* __restrict__ xseq, const float* __restrict__ W,
                           const float* __restrict__ bias, float* __restrict__ seqout) {
    int n = blockIdx.x * blockDim.x + threadIdx.x;       // over T*7*N
    int t = n / (7 * NN);
    int rem = n - t * (7 * NN);
    int b = 1 + rem / NN;
    int j = rem - (b - 1) * NN;
    float x = xseq[((size_t)b * TT + t) * NN + j];
    const float w0 = W[0], w1 = W[1], w2 = W[2], w3 = W[3];
    float4 o;
    o.x = fmaxf(w0 * x + bias[0], 0.f);
    o.y = fmaxf(w1 * x + bias[1], 0.f);
    o.z = fmaxf(w2 * x + bias[2], 0.f);
    o.w = fmaxf(w3 * x + bias[3], 0.f);
    *(float4*)(seqout + (size_t)t * BB * DD + (size_t)b * DD + (size_t)j * HH) = o;
}

// ---------------- LSTM ----------------

__global__ void k_init(float* __restrict__ p) {
    int i = blockIdx.x * blockDim.x + threadIdx.x;
    p[i] = 0.f;
}

// One step: z = x_t @ w_ih^T + h @ w_hh^T (+biases); gate update; write h_out, c.
// 256 blocks (one per 8 d-values), 512 threads (8 waves). Each wave: one gate,
// 4 consecutive rows computed jointly (amortizes LDS reads of x/h 4x).
__global__ __launch_bounds__(512) void k_lstm_step(
    const float* __restrict__ xt, const float* __restrict__ w_ih,
    const float* __restrict__ w_hh, const float* __restrict__ b_ih,
    const float* __restrict__ b_hh, const float* __restrict__ h_in,
    float* __restrict__ h_out, float* __restrict__ c) {
    __shared__ float4 xs4[BB * DD / 4];   // 64 KB
    __shared__ float4 hs4[BB * DD / 4];   // 64 KB
    __shared__ float zbuf[4][8][BB];      // [gate][d_local][b]

    const int tid = threadIdx.x;
    const float4* xg = (const float4*)xt;
    const float4* hg = (const float4*)h_in;
#pragma unroll
    for (int i = 0; i < 8; ++i) {
        xs4[tid + 512 * i] = xg[tid + 512 * i];
        hs4[tid + 512 * i] = hg[tid + 512 * i];
    }
    __syncthreads();

    const int wave = tid >> 6;
    const int lane = tid & 63;
    const int d0 = blockIdx.x * 8;
    const int gate = wave >> 1;           // 0..3
    const int jb = (wave & 1) * 4;        // 0 or 4
    const int r0 = (gate << 11) + d0 + jb;

    const float4* wi0 = (const float4*)(w_ih + (size_t)r0 * DD);
    const float4* wh0 = (const float4*)(w_hh + (size_t)r0 * DD);

    float acc[4][8];
#pragma unroll
    for (int jr = 0; jr < 4; ++jr)
#pragma unroll
        for (int b = 0; b < 8; ++b) acc[jr][b] = 0.f;

#pragma unroll 2
    for (int it = 0; it < 8; ++it) {
        const int k4 = it * 64 + lane;
        float4 wi[4], wh[4];
#pragma unroll
        for (int jr = 0; jr < 4; ++jr) {
            wi[jr] = wi0[jr * 512 + k4];
            wh[jr] = wh0[jr * 512 + k4];
        }
#pragma unroll
        for (int b = 0; b < 8; ++b) {
            float4 xv = xs4[b * 512 + k4];
            float4 hv = hs4[b * 512 + k4];
#pragma unroll
            for (int jr = 0; jr < 4; ++jr) {
                acc[jr][b] += wi[jr].x * xv.x + wi[jr].y * xv.y +
                              wi[jr].z * xv.z + wi[jr].w * xv.w +
                              wh[jr].x * hv.x + wh[jr].y * hv.y +
                              wh[jr].z * hv.z + wh[jr].w * hv.w;
            }
        }
    }

    // butterfly reduce each accumulator across the 64-lane wave
#pragma unroll
    for (int jr = 0; jr < 4; ++jr)
#pragma unroll
        for (int b = 0; b < 8; ++b) {
            float v = acc[jr][b];
            v += __shfl_xor(v, 32, 64);
            v += __shfl_xor(v, 16, 64);
            v += __shfl_xor(v, 8, 64);
            v += __shfl_xor(v, 4, 64);
            v += __shfl_xor(v, 2, 64);
            v += __shfl_xor(v, 1, 64);
            acc[jr][b] = v;
        }

    if (lane == 0) {
#pragma unroll
        for (int jr = 0; jr < 4; ++jr) {
            const int r = r0 + jr;
            const float bsum = b_ih[r] + b_hh[r];
#pragma unroll
            for (int b = 0; b < 8; ++b) zbuf[gate][jb + jr][b] = acc[jr][b] + bsum;
        }
    }
    __syncthreads();

    if (tid < 64) {
        const int dl = tid & 7;
        const int b = tid >> 3;
        const int d = d0 + dl;
        const float zi = zbuf[0][dl][b];
        const float zf = zbuf[1][dl][b];
        const float zg = zbuf[2][dl][b];
        const float zo = zbuf[3][dl][b];
        float cc = c[b * DD + d];
        const float si = 1.f / (1.f + expf(-zi));
        const float sf = 1.f / (1.f + expf(-zf));
        const float so = 1.f / (1.f + expf(-zo));
        const float tg = tanhf(zg);
        cc = sf * cc + si * tg;
        c[b * DD + d] = cc;
        h_out[b * DD + d] = so * tanhf(cc);
    }
}

// ---------------- Final linear: out[b,o] = h[b,:]·w_lin[o,:] + b_lin[o] ----------------
__global__ void k_final(const float* __restrict__ h, const float* __restrict__ w_lin,
                        const float* __restrict__ b_lin, float* __restrict__ out) {
    const int wave = threadIdx.x >> 6;
    const int lane = threadIdx.x & 63;
    const int o = blockIdx.x * 4 + wave;   // 128 blocks x 4 waves = 512 outputs
    const float4* w4 = (const float4*)(w_lin + (size_t)o * DD);
    const float4* h4 = (const float4*)h;

    float acc[8];
#pragma unroll
    for (int b = 0; b < 8; ++b) acc[b] = 0.f;
#pragma unroll 2
    for (int it = 0; it < 8; ++it) {
        const int k4 = it * 64 + lane;
        float4 wv = w4[k4];
#pragma unroll
        for (int b = 0; b < 8; ++b) {
            float4 hv = h4[b * 512 + k4];
            acc[b] += wv.x * hv.x + wv.y * hv.y + wv.z * hv.z + wv.w * hv.w;
        }
    }
#pragma unroll
    for (int b = 0; b < 8; ++b) {
        float v = acc[b];
        v += __shfl_xor(v, 32, 64);
        v += __shfl_xor(v, 16, 64);
        v += __shfl_xor(v, 8, 64);
        v += __shfl_xor(v, 4, 64);
        v += __shfl_xor(v, 2, 64);
        v += __shfl_xor(v, 1, 64);
        acc[b] = v;
    }
    if (lane < 8) out[(size_t)lane * NN + o] = acc[lane] + b_lin[o];
}

// ---------------- launch ----------------

extern "C" void kernel_launch(void* const* d_in, const int* in_sizes, int n_in,
                              void* d_out, int out_size, void* d_ws, size_t ws_size,
                              hipStream_t stream) {
    const float* xseq  = (const float*)d_in[0];   // [B,T,N]
    const float* gat_w = (const float*)d_in[1];   // [4,1]
    const float* a_src = (const float*)d_in[2];   // [4]
    const float* a_dst = (const float*)d_in[3];   // [4]
    const float* g_b   = (const float*)d_in[4];   // [4]
    const float* w_ih  = (const float*)d_in[5];   // [8192,2048]
    const float* w_hh  = (const float*)d_in[6];   // [8192,2048]
    const float* b_ih  = (const float*)d_in[7];   // [8192]
    const float* b_hh  = (const float*)d_in[8];   // [8192]
    const float* w_lin = (const float*)d_in[9];   // [512,2048]
    const float* b_lin = (const float*)d_in[10];  // [512]
    const int*   eidx  = (const int*)d_in[11];    // [2,E]
    float* out = (float*)d_out;

    float* ws_f = (float*)d_ws;
    float* seq  = ws_f;                          // T*B*D = 2,097,152 floats
    float* hb0  = seq + (size_t)TT * BB * DD;    // 16384
    float* hb1  = hb0 + BB * DD;                 // 16384
    float* cbuf = hb1 + BB * DD;                 // 16384
    int* counts  = (int*)(cbuf + BB * DD);       // 512
    int* offs    = counts + NN;                  // 513
    int* fill    = offs + NN + 1;                // 512
    int* csr_src = fill + NN;                    // E

    // CSR build
    k_csr_zero<<<1, NN, 0, stream>>>(counts, fill);
    k_csr_count<<<EE / 256, 256, 0, stream>>>(eidx, counts);
    k_csr_scan<<<1, 1, 0, stream>>>(counts, offs);
    k_csr_fill<<<EE / 256, 256, 0, stream>>>(eidx, offs, fill, csr_src);

    // GAT → seq[T,B,D]
    k_gat0<<<TT, NN, 0, stream>>>(xseq, gat_w, a_src, a_dst, g_b, offs, csr_src, seq);
    k_gat_rest<<<(TT * 7 * NN) / 256, 256, 0, stream>>>(xseq, gat_w, g_b, seq);

    // zero h0 (ping), h1 (don't-care but cheap), c
    k_init<<<(3 * BB * DD) / 256, 256, 0, stream>>>(hb0);

    // LSTM: 128 sequential steps, ping-pong h
    for (int t = 0; t < TT; ++t) {
        float* hin  = (t & 1) ? hb1 : hb0;
        float* hout = (t & 1) ? hb0 : hb1;
        k_lstm_step<<<256, 512, 0, stream>>>(seq + (size_t)t * BB * DD, w_ih, w_hh,
                                             b_ih, b_hh, hin, hout, cbuf);
    }

    // final h is in hb0 after 128 steps
    k_final<<<NN / 4, 256, 0, stream>>>(hb0, w_lin, b_lin, out);
}

// Round 2
// 2555.997 us; speedup vs baseline: 1.6464x; 1.6464x over previous
//
#include <hip/hip_runtime.h>
#include <math.h>

#define BB 8
#define TT 128
#define NN 512
#define HH 4
#define DD 2048      // N*HID
#define EE 16384
#define KTOT 4096    // 2048 (x) + 2048 (h)
#define NKB 128      // KTOT/32 kblocks

typedef __attribute__((ext_vector_type(8))) short short8;
typedef __attribute__((ext_vector_type(4))) float f32x4;

__device__ __forceinline__ float b2f(unsigned short u) {
    union { unsigned int i; float f; } v; v.i = ((unsigned int)u) << 16; return v.f;
}
__device__ __forceinline__ unsigned short f2b(float f) {
    union { float f; unsigned int i; } v; v.f = f;
    unsigned int r = v.i + 0x7fff + ((v.i >> 16) & 1);
    return (unsigned short)(r >> 16);
}

// ---------------- CSR build (edges identical every timestep) ----------------

__global__ void k_csr_zero(int* __restrict__ counts, int* __restrict__ fill) {
    int i = threadIdx.x;
    counts[i] = 0;
    fill[i] = 0;
}

__global__ void k_csr_count(const int* __restrict__ ei, int* __restrict__ counts) {
    int e = blockIdx.x * blockDim.x + threadIdx.x;
    if (e < EE) atomicAdd(&counts[ei[EE + e]], 1);
}

__global__ void k_csr_scan(const int* __restrict__ counts, int* __restrict__ offs) {
    int s = 0;
    for (int i = 0; i < NN; ++i) { offs[i] = s; s += counts[i]; }
    offs[NN] = s;
}

__global__ void k_csr_fill(const int* __restrict__ ei, const int* __restrict__ offs,
                           int* __restrict__ fill, int* __restrict__ csr_src) {
    int e = blockIdx.x * blockDim.x + threadIdx.x;
    if (e < EE) {
        int d = ei[EE + e];
        int pos = atomicAdd(&fill[d], 1);
        csr_src[offs[d] + pos] = ei[e];
    }
}

// ---------------- GAT (outputs bf16 seq[t][b][d]) ----------------

__global__ void k_gat0(const float* __restrict__ xseq, const float* __restrict__ W,
                       const float* __restrict__ as, const float* __restrict__ ad,
                       const float* __restrict__ bias, const int* __restrict__ offs,
                       const int* __restrict__ csr_src, unsigned short* __restrict__ seqout) {
    __shared__ float xr[NN];
    const int t = blockIdx.x;
    const int j = threadIdx.x;
    xr[j] = xseq[t * NN + j];
    __syncthreads();

    const float w0 = W[0], w1 = W[1], w2 = W[2], w3 = W[3];
    const float cs = w0 * as[0] + w1 * as[1] + w2 * as[2] + w3 * as[3];
    const float cd = w0 * ad[0] + w1 * ad[1] + w2 * ad[2] + w3 * ad[3];

    const float xj = xr[j];
    const float ed = cd * xj;
    float e0 = (cs + cd) * xj;
    e0 = e0 > 0.f ? e0 : 0.2f * e0;

    const int s0 = offs[j], s1 = offs[j + 1];
    float m = e0;
    for (int p = s0; p < s1; ++p) {
        float e = cs * xr[csr_src[p]] + ed;
        e = e > 0.f ? e : 0.2f * e;
        m = fmaxf(m, e);
    }
    float den = expf(e0 - m);
    float num = den * xj;
    for (int p = s0; p < s1; ++p) {
        int s = csr_src[p];
        float e = cs * xr[s] + ed;
        e = e > 0.f ? e : 0.2f * e;
        float wgt = expf(e - m);
        den += wgt;
        num += wgt * xr[s];
    }
    const float y = num / den;

    ushort4 o;
    o.x = f2b(fmaxf(w0 * y + bias[0], 0.f));
    o.y = f2b(fmaxf(w1 * y + bias[1], 0.f));
    o.z = f2b(fmaxf(w2 * y + bias[2], 0.f));
    o.w = f2b(fmaxf(w3 * y + bias[3], 0.f));
    *(ushort4*)(seqout + (size_t)t * BB * DD + (size_t)j * HH) = o;
}

__global__ void k_gat_rest(const float* __restrict__ xseq, const float* __restrict__ W,
                           const float* __restrict__ bias, unsigned short* __restrict__ seqout) {
    int n = blockIdx.x * blockDim.x + threadIdx.x;
    int t = n / (7 * NN);
    int rem = n - t * (7 * NN);
    int b = 1 + rem / NN;
    int j = rem - (b - 1) * NN;
    float x = xseq[((size_t)b * TT + t) * NN + j];
    const float w0 = W[0], w1 = W[1], w2 = W[2], w3 = W[3];
    ushort4 o;
    o.x = f2b(fmaxf(w0 * x + bias[0], 0.f));
    o.y = f2b(fmaxf(w1 * x + bias[1], 0.f));
    o.z = f2b(fmaxf(w2 * x + bias[2], 0.f));
    o.w = f2b(fmaxf(w3 * x + bias[3], 0.f));
    *(ushort4*)(seqout + (size_t)t * BB * DD + (size_t)b * DD + (size_t)j * HH) = o;
}

// ---------------- weight pack: f32 [8192][2048]x2 -> bf16 B-fragment tiles ----------------
// Strip s (0..511): 16 rows = {gate*2048 + d : gate=n>>2, d=(s>>1)*8+(s&1)*4+(n&3)}, n=0..15.
// Fragment for (s, kb): lane L holds B[k=kb*32+(L>>4)*8+j][n=L&15], j=0..7 (16 B).
// Stored frag-major: WP[(s*128+kb)*64 + L] (uint4), so the step kernel's wave load
// is one fully-coalesced global_load_dwordx4 (1 KB/instr).
__global__ __launch_bounds__(256) void k_pack_w(const float* __restrict__ wih,
                                                const float* __restrict__ whh,
                                                unsigned short* __restrict__ WP) {
    const int pair = blockIdx.x * 4 + (threadIdx.x >> 6);  // (s,kb): 0..65535
    const int lane = threadIdx.x & 63;
    const int s = pair >> 7, kb = pair & 127;
    const int n = lane & 15, quad = lane >> 4;
    const int d = (s >> 1) * 8 + (s & 1) * 4 + (n & 3);
    const int row = (n >> 2) * 2048 + d;
    const int k = kb * 32 + quad * 8;
    const float* src = (k < 2048) ? (wih + (size_t)row * 2048 + k)
                                  : (whh + (size_t)row * 2048 + (k - 2048));
    unsigned int u[4];
#pragma unroll
    for (int p = 0; p < 4; ++p)
        u[p] = (unsigned int)f2b(src[2 * p]) | ((unsigned int)f2b(src[2 * p + 1]) << 16);
    ((uint4*)WP)[(size_t)pair * 64 + lane] = make_uint4(u[0], u[1], u[2], u[3]);
}

// ---------------- misc ----------------

__global__ void k_init(float* __restrict__ p) {
    int i = blockIdx.x * blockDim.x + threadIdx.x;
    p[i] = 0.f;
}

// ---------------- LSTM step (MFMA) ----------------
// 256 blocks x 512 thr. Block b: d-range d0=8b..8b+7, all 4 gates = strips 2b, 2b+1.
// Wave w: strip st=w>>2, k-quarter q=w&3 (32 kblocks, 32 MFMAs). Cross-wave LDS reduce.
// MFMA: D[m=batch(16, 8 used)][n=16 strip-cols] += A[XH frags, LDS] * B[weight frags, global].
__global__ __launch_bounds__(512) void k_lstm_step(
    const unsigned short* __restrict__ xt, const unsigned short* __restrict__ WP,
    const float* __restrict__ b_ih, const float* __restrict__ b_hh,
    const unsigned short* __restrict__ h_in, unsigned short* __restrict__ h_out,
    float* __restrict__ c) {
    __shared__ uint4 ldsA4[NKB * 64];        // 128 KB A-fragments
    __shared__ float red[2][4][32][4];       // 4 KB partial D
    __shared__ float zbuf[4][8][8];          // [gate][d_local][batch]

    const int tid = threadIdx.x;
    const int wave = tid >> 6;
    const int lane = tid & 63;
    const int d0 = blockIdx.x * 8;

    // stage XH as A-frags: entry (kb,L): A[m=batch=L&15][k=kb*32+(L>>4)*8+j]
#pragma unroll
    for (int i = 0; i < 16; ++i) {
        const int idx = tid + 512 * i;
        const int kb = idx >> 6, L = idx & 63;
        const int batch = L & 15;
        const int k = kb * 32 + ((L >> 4) << 3);
        uint4 v = make_uint4(0u, 0u, 0u, 0u);
        if (batch < 8) {
            const unsigned short* src = (k < 2048) ? (xt + batch * DD + k)
                                                   : (h_in + batch * DD + (k - 2048));
            v = *(const uint4*)src;
        }
        ldsA4[idx] = v;
    }
    __syncthreads();

    const int st = wave >> 2, q = wave & 3;
    const size_t sglob = (size_t)blockIdx.x * 2 + st;
    const uint4* wp = (const uint4*)WP + (sglob * NKB + q * 32) * 64 + lane;

    f32x4 acc0 = {0.f, 0.f, 0.f, 0.f}, acc1 = {0.f, 0.f, 0.f, 0.f};
#pragma unroll 4
    for (int kb2 = 0; kb2 < 32; kb2 += 2) {
        const int kb = q * 32 + kb2;
        uint4 w0 = wp[0];
        uint4 w1 = wp[64];
        wp += 128;
        uint4 a0u = ldsA4[kb * 64 + lane];
        uint4 a1u = ldsA4[(kb + 1) * 64 + lane];
        short8 a0, a1, b0, b1;
        __builtin_memcpy(&a0, &a0u, 16);
        __builtin_memcpy(&a1, &a1u, 16);
        __builtin_memcpy(&b0, &w0, 16);
        __builtin_memcpy(&b1, &w1, 16);
        acc0 = __builtin_amdgcn_mfma_f32_16x16x32_bf16(a0, b0, acc0, 0, 0, 0);
        acc1 = __builtin_amdgcn_mfma_f32_16x16x32_bf16(a1, b1, acc1, 0, 0, 0);
    }
    f32x4 acc = acc0 + acc1;
    if (lane < 32) *(f32x4*)&red[st][q][lane][0] = acc;
    __syncthreads();

    // reduce 4 k-quarters + bias -> zbuf
    if (tid < 256) {
        const int st2 = tid >> 7;
        const int l2 = (tid & 127) >> 2;
        const int reg = tid & 3;
        float z = red[st2][0][l2][reg] + red[st2][1][l2][reg] +
                  red[st2][2][l2][reg] + red[st2][3][l2][reg];
        const int batch = (l2 >> 4) * 4 + reg;   // quad in {0,1} -> batch 0..7
        const int n = l2 & 15;
        const int gate = n >> 2, dd = n & 3;
        const int d = d0 + st2 * 4 + dd;
        const int row = gate * 2048 + d;
        zbuf[gate][st2 * 4 + dd][batch] = z + b_ih[row] + b_hh[row];
    }
    __syncthreads();

    if (tid < 64) {
        const int dl = tid & 7;
        const int batch = tid >> 3;
        const int d = d0 + dl;
        const float zi = zbuf[0][dl][batch];
        const float zf = zbuf[1][dl][batch];
        const float zg = zbuf[2][dl][batch];
        const float zo = zbuf[3][dl][batch];
        float cc = c[batch * DD + d];
        const float si = 1.f / (1.f + expf(-zi));
        const float sf = 1.f / (1.f + expf(-zf));
        const float so = 1.f / (1.f + expf(-zo));
        const float tg = tanhf(zg);
        cc = sf * cc + si * tg;
        c[batch * DD + d] = cc;
        h_out[batch * DD + d] = f2b(so * tanhf(cc));
    }
}

// ---------------- final linear: out[b,o] = h[b,:]·w_lin[o,:] + b_lin[o] ----------------
__global__ void k_final(const unsigned short* __restrict__ h, const float* __restrict__ w_lin,
                        const float* __restrict__ b_lin, float* __restrict__ out) {
    const int wave = threadIdx.x >> 6;
    const int lane = threadIdx.x & 63;
    const int o = blockIdx.x * 4 + wave;
    const float4* w4 = (const float4*)(w_lin + (size_t)o * DD);

    float acc[8];
#pragma unroll
    for (int b = 0; b < 8; ++b) acc[b] = 0.f;
#pragma unroll 2
    for (int it = 0; it < 8; ++it) {
        const int k4 = it * 64 + lane;
        float4 wv = w4[k4];
#pragma unroll
        for (int b = 0; b < 8; ++b) {
            ushort4 hv = *(const ushort4*)(h + (size_t)b * DD + 4 * (size_t)k4);
            acc[b] += wv.x * b2f(hv.x) + wv.y * b2f(hv.y) +
                      wv.z * b2f(hv.z) + wv.w * b2f(hv.w);
        }
    }
#pragma unroll
    for (int b = 0; b < 8; ++b) {
        float v = acc[b];
        v += __shfl_xor(v, 32, 64);
        v += __shfl_xor(v, 16, 64);
        v += __shfl_xor(v, 8, 64);
        v += __shfl_xor(v, 4, 64);
        v += __shfl_xor(v, 2, 64);
        v += __shfl_xor(v, 1, 64);
        acc[b] = v;
    }
    if (lane < 8) out[(size_t)lane * NN + o] = acc[lane] + b_lin[o];
}

// ---------------- launch ----------------

extern "C" void kernel_launch(void* const* d_in, const int* in_sizes, int n_in,
                              void* d_out, int out_size, void* d_ws, size_t ws_size,
                              hipStream_t stream) {
    const float* xseq  = (const float*)d_in[0];
    const float* gat_w = (const float*)d_in[1];
    const float* a_src = (const float*)d_in[2];
    const float* a_dst = (const float*)d_in[3];
    const float* g_b   = (const float*)d_in[4];
    const float* w_ih  = (const float*)d_in[5];
    const float* w_hh  = (const float*)d_in[6];
    const float* b_ih  = (const float*)d_in[7];
    const float* b_hh  = (const float*)d_in[8];
    const float* w_lin = (const float*)d_in[9];
    const float* b_lin = (const float*)d_in[10];
    const int*   eidx  = (const int*)d_in[11];
    float* out = (float*)d_out;

    // workspace layout (bf16 stored as unsigned short)
    unsigned short* seq = (unsigned short*)d_ws;                 // T*B*D bf16 (4 MB)
    unsigned short* WP  = seq + (size_t)TT * BB * DD;            // 8192*4096 bf16 (64 MB)
    unsigned short* hb0 = WP + (size_t)8192 * KTOT;              // B*D bf16 (32 KB)
    unsigned short* hb1 = hb0 + BB * DD;                         // B*D bf16
    float* cbuf = (float*)(hb1 + BB * DD);                       // B*D f32 (64 KB)
    int* counts  = (int*)(cbuf + BB * DD);
    int* offs    = counts + NN;
    int* fill    = offs + NN + 1;
    int* csr_src = fill + NN;

    // CSR build
    k_csr_zero<<<1, NN, 0, stream>>>(counts, fill);
    k_csr_count<<<EE / 256, 256, 0, stream>>>(eidx, counts);
    k_csr_scan<<<1, 1, 0, stream>>>(counts, offs);
    k_csr_fill<<<EE / 256, 256, 0, stream>>>(eidx, offs, fill, csr_src);

    // weight pack (bf16, B-frag swizzled)
    k_pack_w<<<16384, 256, 0, stream>>>(w_ih, w_hh, WP);

    // GAT -> seq (bf16)
    k_gat0<<<TT, NN, 0, stream>>>(xseq, gat_w, a_src, a_dst, g_b, offs, csr_src, seq);
    k_gat_rest<<<(TT * 7 * NN) / 256, 256, 0, stream>>>(xseq, gat_w, g_b, seq);

    // zero hb0, hb1, cbuf (contiguous: 8192 + 8192 + 16384 f32 words)
    k_init<<<128, 256, 0, stream>>>((float*)hb0);

    // LSTM: 128 sequential steps, ping-pong h
    for (int t = 0; t < TT; ++t) {
        unsigned short* hin  = (t & 1) ? hb1 : hb0;
        unsigned short* hout = (t & 1) ? hb0 : hb1;
        k_lstm_step<<<256, 512, 0, stream>>>(seq + (size_t)t * BB * DD, WP,
                                             b_ih, b_hh, hin, hout, cbuf);
    }

    // final h is in hb0 after 128 steps
    k_final<<<NN / 4, 256, 0, stream>>>(hb0, w_lin, b_lin, out);
}